// Round 4
// baseline (198.090 us; speedup 1.0000x reference)
//
#include <hip/hip_runtime.h>

#define NODES  28
#define PPN    320              // points per node
#define MID    13               // (NODES-2)/2
#define NPTS   (NODES * PPN)    // 8960
#define TOTPTS (2 * NPTS)       // 17920
#define SIGMA  10.0f
#define FLT_BIG 3.4e38f

#define BT      128             // threads per block (2 waves)
#define RPT     2               // source points per thread
#define GPTS    (BT * RPT)      // 256 source points per group
#define NGRP    (NPTS / GPTS)   // 35 source groups per direction
#define NGROUPS (2 * NGRP)      // 70 (direction, group) pairs
#define NBLK    (NGROUPS * NODES)  // 1960 blocks

// Module-static scratch (NOT d_ws): the harness unconditionally re-poisons the
// 256 MiB workspace every iteration (~40 us fill at 85% HBM peak, rounds 0-3).
// g_m is fully overwritten each launch before it is read.
__device__ float g_m[NODES][TOTPTS];          // 2.0 MB
__device__ float g_part[NGROUPS];             // per-group partial sums
// Monotonic counters (zero-init at module load, never reset; detection is
// modular: +28/iter per g_arrive entry, +70/iter for g_tailcnt. Wraps only
// after >100M iterations - far beyond any bench run).
__device__ unsigned int g_arrive[NGROUPS];
__device__ unsigned int g_tailcnt;

__inline__ __device__ float wave_reduce_sum(float v) {
    #pragma unroll
    for (int off = 32; off > 0; off >>= 1)
        v += __shfl_down(v, off, 64);
    return v;
}

// ---------------------------------------------------------------------------
// Single fused kernel. Block (p, g, b):
//   phase A: clip+pack db node b into LDS; compute min-dist of its 256 source
//            points (group (p,g)) against node b; write g_m[b][q].
//   phase B: threadfence + arrival atomic on g_arrive[p*NGRP+g]. The 28th
//            arriver of the group is the only block whose combine inputs
//            g_m[0..27][q] are all published -> it folds the closed form for
//            the group's 256 points (L2-hot) and publishes a partial.
//            The 70th partial-publisher sums all partials -> *out.
// No second dispatch, no grid barrier, no spin, no out-zeroing ordering hack.
// ---------------------------------------------------------------------------
__global__ __launch_bounds__(BT)
void chamfer_fused(const float* __restrict__ X, const float* __restrict__ T,
                   float* __restrict__ out)
{
    __shared__ float4 st[PPN];
    __shared__ float  redf[2];
    __shared__ int    s_tail;

    const int bid = blockIdx.x;              // 0 .. NBLK-1
    const int p   = bid / (NGRP * NODES);    // 0: X queries vs T db; 1: T vs X
    const int r   = bid % (NGRP * NODES);
    const int g   = r / NODES;               // source group (256 pts)
    const int b   = r % NODES;               // db node
    const int pg  = p * NGRP + g;

    const float* __restrict__ src = p ? T : X;
    const float* __restrict__ db  = p ? X : T;

    const int t = threadIdx.x;

    // ---- phase A: pairwise min (identical to the verified round-1 kernel) --
    for (int j = t; j < PPN; j += BT) {
        const float* q = db + (size_t)(b * PPN + j) * 3;
        float v0 = fminf(fmaxf(q[0], -SIGMA), SIGMA);
        float v1 = fminf(fmaxf(q[1], -SIGMA), SIGMA);
        float v2 = fminf(fmaxf(q[2], -SIGMA), SIGMA);
        float n  = v0*v0 + v1*v1 + v2*v2;
        st[j] = make_float4(-2.f*v0, -2.f*v1, -2.f*v2, n);
    }

    const int i0 = g * GPTS + t;
    const int i1 = i0 + BT;
    float4 s0, s1;
    {
        const float* q0p = src + (size_t)i0 * 3;
        float a0 = fminf(fmaxf(q0p[0], -SIGMA), SIGMA);
        float a1 = fminf(fmaxf(q0p[1], -SIGMA), SIGMA);
        float a2 = fminf(fmaxf(q0p[2], -SIGMA), SIGMA);
        s0 = make_float4(a0, a1, a2, a0*a0 + a1*a1 + a2*a2);
        const float* q1p = src + (size_t)i1 * 3;
        float b0 = fminf(fmaxf(q1p[0], -SIGMA), SIGMA);
        float b1 = fminf(fmaxf(q1p[1], -SIGMA), SIGMA);
        float b2 = fminf(fmaxf(q1p[2], -SIGMA), SIGMA);
        s1 = make_float4(b0, b1, b2, b0*b0 + b1*b1 + b2*b2);
    }
    __syncthreads();

    float mn0 = FLT_BIG, mn1 = FLT_BIG;
    #pragma unroll 4
    for (int j = 0; j < PPN; j += 2) {
        const float4 ta = st[j];
        const float4 tb = st[j + 1];
        float d0a = fmaf(ta.x, s0.x, fmaf(ta.y, s0.y, fmaf(ta.z, s0.z, ta.w)));
        float d0b = fmaf(tb.x, s0.x, fmaf(tb.y, s0.y, fmaf(tb.z, s0.z, tb.w)));
        float d1a = fmaf(ta.x, s1.x, fmaf(ta.y, s1.y, fmaf(ta.z, s1.z, ta.w)));
        float d1b = fmaf(tb.x, s1.x, fmaf(tb.y, s1.y, fmaf(tb.z, s1.z, tb.w)));
        mn0 = fminf(mn0, fminf(d0a, d0b));   // -> v_min3_f32
        mn1 = fminf(mn1, fminf(d1a, d1b));
    }

    const int q0 = p * NPTS + i0;            // global point id
    g_m[b][q0]      = mn0 + s0.w;
    g_m[b][q0 + BT] = mn1 + s1.w;

    // ---- phase B: arrival + last-block combine --------------------------
    __threadfence();                         // release this thread's g_m writes
    __syncthreads();                         // all threads' fences done
    if (t == 0) {
        unsigned int old = atomicAdd(&g_arrive[pg], 1u);
        s_tail = ((old % NODES) == NODES - 1) ? 1 : 0;
    }
    __syncthreads();
    if (!s_tail) return;

    __threadfence();                         // acquire other blocks' g_m rows

    float tot = 0.0f;
    #pragma unroll
    for (int k = 0; k < RPT; ++k) {
        const int ql = g * GPTS + t + k * BT;   // local point id (< NPTS)
        const int q  = p * NPTS + ql;
        const int a  = ql / PPN;                // node of this point

        float rr[NODES];
        #pragma unroll
        for (int c = 0; c < NODES; ++c) rr[c] = g_m[c][q];

        float min1 = FLT_BIG; int c1 = -1;
        #pragma unroll
        for (int c = 0; c < NODES; ++c) {
            if (rr[c] < min1) { min1 = rr[c]; c1 = c; }
        }
        float min2 = FLT_BIG;
        #pragma unroll
        for (int c = 0; c < NODES; ++c) {
            float v = (c == c1) ? FLT_BIG : rr[c];
            min2 = fminf(min2, v);
        }
        float H = FLT_BIG;
        if (a < MID) {
            #pragma unroll
            for (int c = 0; c < MID; ++c) H = fminf(H, rr[c]);
        } else {
            #pragma unroll
            for (int c = MID; c < NODES; ++c) H = fminf(H, rr[c]);
        }

        const int n = (a < NODES - 2) ? (NODES - 3) : (NODES - 2); // 25 or 26
        float S = (float)n * min1;
        if (c1 <= NODES - 3 && c1 != a) S -= (min1 - min2);
        if (a < NODES - 2) {
            const int dup = (a < MID) ? (a + MID) : (a - MID);
            S += (c1 == dup) ? min2 : min1;
        }
        tot += S + H;
    }

    // block reduce (2 waves)
    float ws = wave_reduce_sum(tot);
    const int lane = t & 63;
    const int wid  = t >> 6;
    if (lane == 0) redf[wid] = ws;
    __syncthreads();
    if (t == 0) {
        float bs = redf[0] + redf[1];
        atomicExch(&g_part[pg], bs);         // device-scope publish
        __threadfence();
        unsigned int old = atomicAdd(&g_tailcnt, 1u);
        if ((old % NGROUPS) == NGROUPS - 1) {
            __threadfence();                 // acquire all g_part
            float s = 0.0f;
            for (int i = 0; i < NGROUPS; ++i)
                s += atomicAdd(&g_part[i], 0.0f);   // coherent read
            *out = s;
        }
    }
}

extern "C" void kernel_launch(void* const* d_in, const int* in_sizes, int n_in,
                              void* d_out, int out_size, void* d_ws, size_t ws_size,
                              hipStream_t stream) {
    const float* X = (const float*)d_in[0];
    const float* T = (const float*)d_in[1];
    float* out = (float*)d_out;
    (void)d_ws; (void)ws_size;               // workspace intentionally unused

    chamfer_fused<<<NBLK, BT, 0, stream>>>(X, T, out);
}

// Round 5
// 74.471 us; speedup vs baseline: 2.6600x; 2.6600x over previous
//
#include <hip/hip_runtime.h>

#define NODES  28
#define PPN    320              // points per node
#define MID    13               // (NODES-2)/2
#define NPTS   (NODES * PPN)    // 8960
#define TOTPTS (2 * NPTS)       // 17920
#define SIGMA  10.0f
#define FLT_BIG 3.4e38f

#define BT    128               // threads per pair block (2 waves)
#define RPT   2                 // source points per thread
#define GPTS  (BT * RPT)        // 256 source points per block
#define NGRP  (NPTS / GPTS)     // 35 source groups per direction

// Inter-phase scratch in module-static device memory (NOT d_ws): the harness
// unconditionally re-poisons the 256 MiB workspace every iteration (~40 us
// fillBufferAligned at ~6.7 TB/s, confirmed rounds 0-4). g_m is fully
// overwritten by pair_min_kernel before combine_kernel reads it; the kernel
// boundary between the two dispatches provides cross-XCD visibility for free
// (R4 showed explicit per-block __threadfence() costs 15x kernel time).
__device__ float g_m[NODES][TOTPTS];   // 2.0 MB

// ---------------------------------------------------------------------------
// Phase 1 (fused prep + pairwise min): one block per
// (direction p, source-group g, db-node b). Block clips+packs db node b's
// 320 points into LDS as (-2x,-2y,-2z,|x|^2); each thread owns 2 clipped
// source points (x,y,z,|x|^2 in regs). dist^2 = dot(db.xyz, s.xyz) + db.w
// (+ s.w added once after the min). Inner loop: 2 db points per step so the
// two fmins fuse to v_min3_f32 -> 3.5 VALU/distance (the arithmetic floor
// for this closed form). Output m[b][q] is lane-coalesced. Block 0 zeroes
// the output accumulator (stream ordering puts it before combine's atomics).
// ---------------------------------------------------------------------------
__global__ __launch_bounds__(BT)
void pair_min_kernel(const float* __restrict__ X, const float* __restrict__ T,
                     float* __restrict__ out)
{
    __shared__ float4 st[PPN];

    const int bid = blockIdx.x;              // 0 .. 2*NGRP*NODES-1
    const int p   = bid / (NGRP * NODES);    // 0: X queries vs T db; 1: T vs X
    const int r   = bid % (NGRP * NODES);
    const int g   = r / NODES;               // source group (256 pts)
    const int b   = r % NODES;               // db node

    const float* __restrict__ src = p ? T : X;
    const float* __restrict__ db  = p ? X : T;

    const int t = threadIdx.x;

    if (bid == 0 && t == 0) *out = 0.0f;     // zero accumulator for phase 2

    // stage + clip + pack db node b (320 pts)
    for (int j = t; j < PPN; j += BT) {
        const float* q = db + (size_t)(b * PPN + j) * 3;
        float v0 = fminf(fmaxf(q[0], -SIGMA), SIGMA);
        float v1 = fminf(fmaxf(q[1], -SIGMA), SIGMA);
        float v2 = fminf(fmaxf(q[2], -SIGMA), SIGMA);
        float n  = v0*v0 + v1*v1 + v2*v2;
        st[j] = make_float4(-2.f*v0, -2.f*v1, -2.f*v2, n);
    }

    // own source points (clip + norm)
    const int i0 = g * GPTS + t;
    const int i1 = i0 + BT;
    float4 s0, s1;
    {
        const float* q0 = src + (size_t)i0 * 3;
        float a0 = fminf(fmaxf(q0[0], -SIGMA), SIGMA);
        float a1 = fminf(fmaxf(q0[1], -SIGMA), SIGMA);
        float a2 = fminf(fmaxf(q0[2], -SIGMA), SIGMA);
        s0 = make_float4(a0, a1, a2, a0*a0 + a1*a1 + a2*a2);
        const float* q1 = src + (size_t)i1 * 3;
        float b0 = fminf(fmaxf(q1[0], -SIGMA), SIGMA);
        float b1 = fminf(fmaxf(q1[1], -SIGMA), SIGMA);
        float b2 = fminf(fmaxf(q1[2], -SIGMA), SIGMA);
        s1 = make_float4(b0, b1, b2, b0*b0 + b1*b1 + b2*b2);
    }
    __syncthreads();

    float mn0 = FLT_BIG, mn1 = FLT_BIG;
    #pragma unroll 4
    for (int j = 0; j < PPN; j += 2) {
        const float4 ta = st[j];
        const float4 tb = st[j + 1];
        float d0a = fmaf(ta.x, s0.x, fmaf(ta.y, s0.y, fmaf(ta.z, s0.z, ta.w)));
        float d0b = fmaf(tb.x, s0.x, fmaf(tb.y, s0.y, fmaf(tb.z, s0.z, tb.w)));
        float d1a = fmaf(ta.x, s1.x, fmaf(ta.y, s1.y, fmaf(ta.z, s1.z, ta.w)));
        float d1b = fmaf(tb.x, s1.x, fmaf(tb.y, s1.y, fmaf(tb.z, s1.z, tb.w)));
        mn0 = fminf(mn0, fminf(d0a, d0b));   // -> v_min3_f32
        mn1 = fminf(mn1, fminf(d1a, d1b));
    }

    const int q0 = p * NPTS + i0;            // global point id
    g_m[b][q0]      = mn0 + s0.w;
    g_m[b][q0 + BT] = mn1 + s1.w;
}

__inline__ __device__ float wave_reduce_sum(float v) {
    #pragma unroll
    for (int off = 32; off > 0; off >>= 1)
        v += __shfl_down(v, off, 64);
    return v;
}

// ---------------------------------------------------------------------------
// Phase 2: fold the 28 per-node minima into the 26-subset closed form +
// half-arch term; reduce to scalar. g_m[c][q]: for fixed c, lanes read
// consecutive q -> coalesced.
// ---------------------------------------------------------------------------
__global__ __launch_bounds__(256)
void combine_kernel(float* __restrict__ out)
{
    const int q = blockIdx.x * blockDim.x + threadIdx.x;  // 0 .. TOTPTS-1
    float tot = 0.0f;
    if (q < TOTPTS) {
        const int a = (q % NPTS) / PPN;   // node of this point

        float r[NODES];
        #pragma unroll
        for (int c = 0; c < NODES; ++c) r[c] = g_m[c][q];

        // min1 / argmin
        float min1 = FLT_BIG; int c1 = -1;
        #pragma unroll
        for (int c = 0; c < NODES; ++c) {
            if (r[c] < min1) { min1 = r[c]; c1 = c; }
        }
        // min over c != c1
        float min2 = FLT_BIG;
        #pragma unroll
        for (int c = 0; c < NODES; ++c) {
            float v = (c == c1) ? FLT_BIG : r[c];
            min2 = fminf(min2, v);
        }
        // half-arch min
        float H = FLT_BIG;
        if (a < MID) {
            #pragma unroll
            for (int c = 0; c < MID; ++c) H = fminf(H, r[c]);
        } else {
            #pragma unroll
            for (int c = MID; c < NODES; ++c) H = fminf(H, r[c]);
        }

        const int n = (a < NODES - 2) ? (NODES - 3) : (NODES - 2); // 25 or 26
        float S = (float)n * min1;
        if (c1 <= NODES - 3 && c1 != a) S -= (min1 - min2);
        if (a < NODES - 2) {
            const int dup = (a < MID) ? (a + MID) : (a - MID);
            S += (c1 == dup) ? min2 : min1;
        }
        tot = S + H;
    }

    __shared__ float warp_sums[4];
    float ws = wave_reduce_sum(tot);
    const int lane = threadIdx.x & 63;
    const int wid  = threadIdx.x >> 6;
    if (lane == 0) warp_sums[wid] = ws;
    __syncthreads();
    if (wid == 0) {
        float v = (lane < 4) ? warp_sums[lane] : 0.0f;
        v = wave_reduce_sum(v);
        if (lane == 0) atomicAdd(out, v);
    }
}

extern "C" void kernel_launch(void* const* d_in, const int* in_sizes, int n_in,
                              void* d_out, int out_size, void* d_ws, size_t ws_size,
                              hipStream_t stream) {
    const float* X = (const float*)d_in[0];
    const float* T = (const float*)d_in[1];
    float* out = (float*)d_out;
    (void)d_ws; (void)ws_size;               // workspace intentionally unused

    pair_min_kernel<<<2 * NGRP * NODES, BT, 0, stream>>>(X, T, out);
    combine_kernel<<<(TOTPTS + 255) / 256, 256, 0, stream>>>(out);
}